// Round 7
// baseline (229.377 us; speedup 1.0000x reference)
//
#include <hip/hip_runtime.h>
#include <math.h>

#define DIM 1024
#define NH 16
#define HD 64
#define TT 2048
#define NTOK 4096   // B*T

typedef __bf16 bf8v __attribute__((ext_vector_type(8)));
typedef float f4v __attribute__((ext_vector_type(4)));
typedef float f16v __attribute__((ext_vector_type(16)));
typedef unsigned short us8 __attribute__((ext_vector_type(8)));
typedef unsigned short us4 __attribute__((ext_vector_type(4)));
typedef unsigned int u4v __attribute__((ext_vector_type(4)));

static __device__ __forceinline__ unsigned short f2bf(float f) {
    unsigned int u = __float_as_uint(f);
    u += 0x7FFFu + ((u >> 16) & 1u);   // RNE
    return (unsigned short)(u >> 16);
}
static __device__ __forceinline__ bf8v ld8(const unsigned short* p) {
    return __builtin_bit_cast(bf8v, *(const us8*)p);
}
// async global->LDS, 16B per lane; HW dest = wave-uniform base + lane*16
static __device__ __forceinline__ void gl_lds(const unsigned short* g, unsigned short* l) {
    __builtin_amdgcn_global_load_lds((const __attribute__((address_space(1))) unsigned int*)(g),
                                     (__attribute__((address_space(3))) unsigned int*)(l), 16, 0, 0);
}

// ---------- fused prep: x->bf16 | W transpose->bf16 | rope table ----------
__global__ void k_prep(const float* __restrict__ x, unsigned short* __restrict__ xb,
                       const float* __restrict__ Wq, const float* __restrict__ Wk,
                       const float* __restrict__ Wv, unsigned short* __restrict__ wt,
                       float* __restrict__ rope) {
    int tid = threadIdx.x;
    int bb = blockIdx.x;
    if (bb < 4096) {                       // cast x (4 floats/thread)
        int i = bb * 256 + tid;
        float4 v = ((const float4*)x)[i];
        us4 o;
        o[0] = f2bf(v.x); o[1] = f2bf(v.y); o[2] = f2bf(v.z); o[3] = f2bf(v.w);
        *(us4*)&xb[i * 4] = o;
    } else if (bb < 7168) {                // transpose Wq|Wk|Wv
        __shared__ float tile[32][33];
        bb -= 4096;
        int z = bb >> 10, rem = bb & 1023;
        int bx = rem & 31, by = rem >> 5;
        const float* W = (z == 0) ? Wq : ((z == 1) ? Wk : Wv);
        int tx = tid & 31, ty = tid >> 5;   // (32, 8)
        int c0 = bx * 32, k0 = by * 32;
#pragma unroll
        for (int j = 0; j < 4; j++)
            tile[ty + j * 8][tx] = W[(k0 + ty + j * 8) * DIM + c0 + tx];
        __syncthreads();
        unsigned short* out = wt + z * DIM * DIM;
#pragma unroll
        for (int j = 0; j < 4; j++)
            out[(c0 + ty + j * 8) * DIM + k0 + tx] = f2bf(tile[tx][ty + j * 8]);
    } else {                               // rope [TT][HD]
        int i = (bb - 7168) * 256 + tid;
        int s = i >> 6, d = i & 63;
        float inv = exp2f(-(float)(d & 31) * (13.287712379549449f / 32.0f));
        float a = (float)s * inv;
        rope[i] = (d < 32) ? cosf(a) : sinf(a);
    }
}

// ---------------- R = rope^T rope (64x64), s-parallel x4 ----------------
__global__ void k_R(const float* __restrict__ rope, float* __restrict__ R) {
    __shared__ float red[256];
    int d = blockIdx.x;
    int e = threadIdx.x & 63, sl = threadIdx.x >> 6;
    const float* rp = rope + sl * 512 * 64;
    float acc = 0.f;
    for (int s = 0; s < 512; s++)
        acc += rp[s * 64 + d] * rp[s * 64 + e];
    red[threadIdx.x] = acc;
    __syncthreads();
    if (sl == 0)
        R[d * 64 + e] = (red[e] + red[e + 64]) + (red[e + 128] + red[e + 192]);
}

// ------------- Wo2t[j][r] = sum_e R[d][e] * Wo[h*64+e][j],  r = h*64+d -------------
__global__ void k_wo2(const float* __restrict__ Wo, const float* __restrict__ R,
                      unsigned short* __restrict__ wo2t) {
    __shared__ float Ws[64 * 65];   // Ws[e][j]
    __shared__ float Rt[64 * 65];   // Rt[e][d] = R[d*64+e]
    int tid = threadIdx.x;
    int h = blockIdx.y, j0 = blockIdx.x * 64;
    for (int idx = tid; idx < 4096; idx += 256) {
        int e = idx >> 6, j = idx & 63;
        Ws[e * 65 + j] = Wo[(h * 64 + e) * DIM + j0 + j];
        Rt[e * 65 + j] = R[j * 64 + e];
    }
    __syncthreads();
    int d = tid & 63, jb = (tid >> 6) * 16;
    float acc[16] = {};
    for (int e = 0; e < 64; e++) {
        float r = Rt[e * 65 + d];
#pragma unroll
        for (int jj = 0; jj < 16; jj++)
            acc[jj] += r * Ws[e * 65 + jb + jj];
    }
#pragma unroll
    for (int jj = 0; jj < 16; jj++)
        wo2t[(j0 + jb + jj) * DIM + h * 64 + d] = f2bf(acc[jj]);
}

// ================= GEMM core (m97-style): global_load_lds staging, XOR-swizzled LDS =================
// LDS layout: row-major [128][32] bf16, but 16B chunk q of row r stored at phys slot q^(r&3).
// Frag read for logical quarter `quad` uses qx = quad^(l16&3) -> bank-uniform (no >2-way conflicts).

// QKV projection: N = 3072. Q (pre-scaled by c1), K scatter to [B][H][T][64];
// V TRANSPOSED to [B][H][64][T].
__global__ __launch_bounds__(256, 3) void k_gemm_qkv(const unsigned short* __restrict__ A,
                                                     const unsigned short* __restrict__ Bt,
                                                     unsigned short* __restrict__ qk,
                                                     unsigned short* __restrict__ vt) {
    __shared__ unsigned short As[128 * 32];
    __shared__ unsigned short Bs[128 * 32];
    const int K = 1024;
    int tid = threadIdx.x;
    int lane = tid & 63, w = tid >> 6;
    int quad = lane >> 4, l16 = lane & 15;
    int m0 = blockIdx.y * 128, n0 = blockIdx.x * 128;
    int wm = (w >> 1) * 64, wn = (w & 1) * 64;

    // two 16B staging chunks per thread, lane-contiguous per wave
    int s0 = tid, s1 = 256 + tid;
    int r0 = s0 >> 2, cc0 = ((s0 & 3) ^ (r0 & 3)) * 8;
    int r1 = s1 >> 2, cc1 = ((s1 & 3) ^ (r1 & 3)) * 8;
    const unsigned short* Ag0 = A + (m0 + r0) * K + cc0;
    const unsigned short* Ag1 = A + (m0 + r1) * K + cc1;
    const unsigned short* Bg0 = Bt + (n0 + r0) * K + cc0;
    const unsigned short* Bg1 = Bt + (n0 + r1) * K + cc1;
    int qx = quad ^ (l16 & 3);

    f4v acc[4][4] = {};
    for (int k0 = 0; k0 < K; k0 += 32) {
        __syncthreads();                       // prior iter frag reads done
        gl_lds(Ag0 + k0, &As[s0 * 8]);
        gl_lds(Ag1 + k0, &As[s1 * 8]);
        gl_lds(Bg0 + k0, &Bs[s0 * 8]);
        gl_lds(Bg1 + k0, &Bs[s1 * 8]);
        __syncthreads();                       // drains vmcnt -> tiles in LDS
        bf8v af[4], bf[4];
#pragma unroll
        for (int mt = 0; mt < 4; mt++)
            af[mt] = ld8(&As[(wm + mt * 16 + l16) * 32 + qx * 8]);
#pragma unroll
        for (int nt = 0; nt < 4; nt++)
            bf[nt] = ld8(&Bs[(wn + nt * 16 + l16) * 32 + qx * 8]);
#pragma unroll
        for (int mt = 0; mt < 4; mt++)
#pragma unroll
            for (int nt = 0; nt < 4; nt++)
                acc[mt][nt] = __builtin_amdgcn_mfma_f32_16x16x32_bf16(af[mt], bf[nt], acc[mt][nt], 0, 0, 0);
    }
#pragma unroll
    for (int mt = 0; mt < 4; mt++) {
#pragma unroll
        for (int nt = 0; nt < 4; nt++) {
            int gc = n0 + wn + nt * 16 + l16;
            int h = (gc >> 6) & 15;
            int d = gc & 63;
            if (gc < 2048) {             // Q or K: [mtx][B][H][T][64]; Q pre-scaled by c1
                float qs = (gc < 1024) ? 0.18033688011111793f : 1.0f;
                int mtx = gc >> 10;
                unsigned short* base = qk + mtx * (NTOK * DIM);
#pragma unroll
                for (int r = 0; r < 4; r++) {
                    int gm = m0 + wm + mt * 16 + quad * 4 + r;
                    int b = gm >> 11, t = gm & 2047;
                    base[((b * NH + h) * TT + t) * HD + d] = f2bf(acc[mt][nt][r] * qs);
                }
            } else {                     // V: transposed [B][H][64][T]
                int gm0 = m0 + wm + mt * 16 + quad * 4;
                int b = gm0 >> 11, t = gm0 & 2047;
                us4 ov;
#pragma unroll
                for (int r = 0; r < 4; r++)
                    ov[r] = f2bf(acc[mt][nt][r]);
                *(us4*)&vt[(((b * NH + h) * HD) + d) * TT + t] = ov;
            }
        }
    }
}

// Output projection with FUSED COMBINE: A = (Op0 + Op1) * inv(token,head), built in-register
// during staging (replaces k_comb). B = Wo2t via gl_lds. inv = 1/(Ls0+Ls1), per (token, head);
// each staged 8-elem chunk lies within one head (cc 8-aligned, k0 32-aligned).
__global__ __launch_bounds__(256, 3) void k_gemm_out(const unsigned short* __restrict__ Op,
                                                     const float* __restrict__ Ls,
                                                     const unsigned short* __restrict__ Bt,
                                                     const float* __restrict__ bo,
                                                     float* __restrict__ out) {
    __shared__ unsigned short As[128 * 32];
    __shared__ unsigned short Bs[128 * 32];
    const int K = 1024;
    int tid = threadIdx.x;
    int lane = tid & 63, w = tid >> 6;
    int quad = lane >> 4, l16 = lane & 15;
    int m0 = blockIdx.y * 128, n0 = blockIdx.x * 128;
    int wm = (w >> 1) * 64, wn = (w & 1) * 64;

    int s0 = tid, s1 = 256 + tid;
    int r0 = s0 >> 2, cc0 = ((s0 & 3) ^ (r0 & 3)) * 8;
    int r1 = s1 >> 2, cc1 = ((s1 & 3) ^ (r1 & 3)) * 8;
    int gm0 = m0 + r0, gm1 = m0 + r1;
    const unsigned short* Ag0 = Op + gm0 * K + cc0;
    const unsigned short* Ag1 = Op + gm1 * K + cc1;
    const unsigned short* Bg0 = Bt + (n0 + r0) * K + cc0;
    const unsigned short* Bg1 = Bt + (n0 + r1) * K + cc1;
    // Ls[sp*65536 + (b*16+h)*2048 + t]; per-thread t,b fixed; h varies with k0
    const float* L0 = Ls + (gm0 >> 11) * 16 * 2048 + (gm0 & 2047);
    const float* L1 = Ls + (gm1 >> 11) * 16 * 2048 + (gm1 & 2047);
    int qx = quad ^ (l16 & 3);

    f4v acc[4][4] = {};
    for (int k0 = 0; k0 < K; k0 += 32) {
        __syncthreads();                       // prior iter frag reads done
        gl_lds(Bg0 + k0, &Bs[s0 * 8]);
        gl_lds(Bg1 + k0, &Bs[s1 * 8]);
        {
            int h0 = (k0 + cc0) >> 6;
            int h1 = (k0 + cc1) >> 6;
            float inv0 = __builtin_amdgcn_rcpf(L0[h0 * 2048] + L0[65536 + h0 * 2048]);
            float inv1 = __builtin_amdgcn_rcpf(L1[h1 * 2048] + L1[65536 + h1 * 2048]);
            us8 a0 = *(const us8*)(Ag0 + k0);
            us8 c0v = *(const us8*)(Ag0 + NTOK * DIM + k0);
            us8 a1 = *(const us8*)(Ag1 + k0);
            us8 c1v = *(const us8*)(Ag1 + NTOK * DIM + k0);
            u4v o0, o1;
#pragma unroll
            for (int p = 0; p < 4; p++) {
                float va = (__uint_as_float((unsigned int)a0[2 * p] << 16) +
                            __uint_as_float((unsigned int)c0v[2 * p] << 16)) * inv0;
                float vb = (__uint_as_float((unsigned int)a0[2 * p + 1] << 16) +
                            __uint_as_float((unsigned int)c0v[2 * p + 1] << 16)) * inv0;
                unsigned int wd;
                asm("v_cvt_pk_bf16_f32 %0, %1, %2" : "=v"(wd) : "v"(va), "v"(vb));
                o0[p] = wd;
                float vc = (__uint_as_float((unsigned int)a1[2 * p] << 16) +
                            __uint_as_float((unsigned int)c1v[2 * p] << 16)) * inv1;
                float vd = (__uint_as_float((unsigned int)a1[2 * p + 1] << 16) +
                            __uint_as_float((unsigned int)c1v[2 * p + 1] << 16)) * inv1;
                asm("v_cvt_pk_bf16_f32 %0, %1, %2" : "=v"(wd) : "v"(vc), "v"(vd));
                o1[p] = wd;
            }
            *(u4v*)&As[s0 * 8] = o0;           // ds_write_b128
            *(u4v*)&As[s1 * 8] = o1;
        }
        __syncthreads();                       // drains vmcnt + lgkmcnt -> tiles in LDS
        bf8v af[4], bf[4];
#pragma unroll
        for (int mt = 0; mt < 4; mt++)
            af[mt] = ld8(&As[(wm + mt * 16 + l16) * 32 + qx * 8]);
#pragma unroll
        for (int nt = 0; nt < 4; nt++)
            bf[nt] = ld8(&Bs[(wn + nt * 16 + l16) * 32 + qx * 8]);
#pragma unroll
        for (int mt = 0; mt < 4; mt++)
#pragma unroll
            for (int nt = 0; nt < 4; nt++)
                acc[mt][nt] = __builtin_amdgcn_mfma_f32_16x16x32_bf16(af[mt], bf[nt], acc[mt][nt], 0, 0, 0);
    }
#pragma unroll
    for (int mt = 0; mt < 4; mt++) {
#pragma unroll
        for (int nt = 0; nt < 4; nt++) {
            int gc = n0 + wn + nt * 16 + l16;
            float bias = bo[gc];
#pragma unroll
            for (int r = 0; r < 4; r++) {
                int gm = m0 + wm + mt * 16 + quad * 4 + r;
                out[gm * DIM + gc] = acc[mt][nt][r] + bias;
            }
        }
    }
}

// ================= flash attention v4 (round-4 proven): 4 blocks/CU, chunk-fused =================
// grid 1024, 256 thr, 32 q-rows/wave. Each SIMD hosts waves from different blocks -> cross-block
// MFMA/VALU overlap. Per 16-key chunk, softmax pack feeds its 2 PV MFMAs immediately.
// Staging: swizzled global source + linear LDS dest (involution p^=(r&7)); dbuf, counted vmcnt(4).
__global__ __launch_bounds__(256, 4) void k_flash(const unsigned short* __restrict__ qk,
                                                  const unsigned short* __restrict__ vt,
                                                  unsigned short* __restrict__ Op,
                                                  float* __restrict__ Ls) {
    __shared__ unsigned short Ks[2][64 * 64];
    __shared__ unsigned short Vs[2][64 * 64];
    int tid = threadIdx.x;
    int lane = tid & 63, w = tid >> 6;
    int q31 = lane & 31, hi = lane >> 5;
    int bid = blockIdx.x;
    int xcd = bid & 7, sl = bid >> 3;
    int bh = xcd * 4 + (sl & 3);
    int qt = (sl >> 2) & 15;
    int sp = sl >> 6;

    const unsigned short* Qg = qk + bh * (TT * HD);
    const unsigned short* Kg = qk + NTOK * DIM + bh * (TT * HD) + sp * 1024 * HD;
    const unsigned short* Vg = vt + bh * (HD * TT) + sp * 1024;

    // Q B-frag (k=dim): lane n=q31 holds Q[qrow][16*ks + 8*hi + j]
    int qrow = qt * 128 + w * 32 + q31;
    bf8v qf[4];
#pragma unroll
    for (int ks = 0; ks < 4; ks++)
        qf[ks] = ld8(Qg + qrow * HD + ks * 16 + hi * 8);

    // staging: 512 chunks of 16B per tile; thread stages chunks tid and 256+tid.
    // chunk idx -> row r=idx>>3, phys slot p=idx&7, logical chunk c=p^(r&7) (involution).
    int r0 = tid >> 3, sw = (tid & 7) ^ (r0 & 7);
    int offK0 = r0 * HD + sw * 8, offK1 = offK0 + 32 * HD;
    int offV0 = r0 * TT + sw * 8, offV1 = offV0 + 32 * TT;
    int dst0 = tid * 8, dst1 = dst0 + 2048;

#define STAGE(tile, bufsel) do {                                  \
        const unsigned short* kb_ = Kg + (tile) * 64 * HD;        \
        const unsigned short* vb_ = Vg + (tile) * 64;             \
        gl_lds(kb_ + offK0, &Ks[bufsel][dst0]);                   \
        gl_lds(kb_ + offK1, &Ks[bufsel][dst1]);                   \
        gl_lds(vb_ + offV0, &Vs[bufsel][dst0]);                   \
        gl_lds(vb_ + offV1, &Vs[bufsel][dst1]);                   \
    } while (0)

    STAGE(0, 0);
    STAGE(1, 1);

    f16v oacc[2] = {};               // [mtd] O^T dim tiles
    float lsg = 0.f;
    int xsw = q31 & 7;

    for (int it = 0; it < 16; it++) {
        int cur = it & 1;
        if (it == 15) { asm volatile("s_waitcnt vmcnt(0)" ::: "memory"); }
        else          { asm volatile("s_waitcnt vmcnt(4)" ::: "memory"); }
        __builtin_amdgcn_s_barrier();
        asm volatile("" ::: "memory");

        const unsigned short* Kb = Ks[cur];
        const unsigned short* Vb = Vs[cur];

        // K frags + QK^T: S^T[key][qrow], 2 key tiles x K=64 (4 steps)
        bf8v kf0[4], kf1[4];
#pragma unroll
        for (int ks = 0; ks < 4; ks++) {
            kf0[ks] = ld8(&Kb[(q31) * 64 + ((2 * ks + hi) ^ xsw) * 8]);
            kf1[ks] = ld8(&Kb[(32 + q31) * 64 + ((2 * ks + hi) ^ xsw) * 8]);
        }
        f16v s0 = {}, s1 = {};
#pragma unroll
        for (int ks = 0; ks < 4; ks++) {
            s0 = __builtin_amdgcn_mfma_f32_32x32x16_bf16(kf0[ks], qf[ks], s0, 0, 0, 0);
            s1 = __builtin_amdgcn_mfma_f32_32x32x16_bf16(kf1[ks], qf[ks], s1, 0, 0, 0);
        }

        // V^T A-frags (ds_read latency hides under softmax chunks)
        bf8v vf[2][4];
#pragma unroll
        for (int kk = 0; kk < 4; kk++) {
            vf[0][kk] = ld8(&Vb[(q31) * 64 + ((2 * kk + hi) ^ xsw) * 8]);
            vf[1][kk] = ld8(&Vb[(32 + q31) * 64 + ((2 * kk + hi) ^ xsw) * 8]);
        }

        // chunk-fused softmax -> PV. Per 16-key chunk kk = mt*2+sub:
        // reg r of s_mt holds S^T[key = 32mt + (r&3)+8(r>>2)+4hi][qrow]; p = 2^s (Q pre-scaled).
        // cvt_pk pairs -> e0..e3 (keys {0,1},{2,3},{8,9},{10,11}+4hi); swap(e0,e2)+swap(e1,e3)
        // -> P^T B-frag words (k=8hi+j). Then 2 PV MFMAs for this chunk overlap next chunk VALU.
#pragma unroll
        for (int mt = 0; mt < 2; mt++) {
#pragma unroll
            for (int sub = 0; sub < 2; sub++) {
                const f16v& s = mt ? s1 : s0;
                float pe[8];
#pragma unroll
                for (int j = 0; j < 8; j++)
                    pe[j] = __builtin_amdgcn_exp2f(s[sub * 8 + j]);
                float t01 = pe[0] + pe[1], t23 = pe[2] + pe[3];
                float t45 = pe[4] + pe[5], t67 = pe[6] + pe[7];
                lsg += (t01 + t23) + (t45 + t67);
                unsigned int e0, e1, e2, e3;
                asm("v_cvt_pk_bf16_f32 %0, %1, %2" : "=v"(e0) : "v"(pe[0]), "v"(pe[1]));
                asm("v_cvt_pk_bf16_f32 %0, %1, %2" : "=v"(e1) : "v"(pe[2]), "v"(pe[3]));
                asm("v_cvt_pk_bf16_f32 %0, %1, %2" : "=v"(e2) : "v"(pe[4]), "v"(pe[5]));
                asm("v_cvt_pk_bf16_f32 %0, %1, %2" : "=v"(e3) : "v"(pe[6]), "v"(pe[7]));
                asm("v_permlane32_swap_b32 %0, %1" : "+v"(e0), "+v"(e2));
                asm("v_permlane32_swap_b32 %0, %1" : "+v"(e1), "+v"(e3));
                u4v pv = {e0, e1, e2, e3};
                bf8v pb = __builtin_bit_cast(bf8v, pv);
                int kk = mt * 2 + sub;
                oacc[0] = __builtin_amdgcn_mfma_f32_32x32x16_bf16(vf[0][kk], pb, oacc[0], 0, 0, 0);
                oacc[1] = __builtin_amdgcn_mfma_f32_32x32x16_bf16(vf[1][kk], pb, oacc[1], 0, 0, 0);
            }
        }

        __builtin_amdgcn_s_barrier();
        asm volatile("" ::: "memory");
        if (it < 14) STAGE(it + 2, cur);
    }
#undef STAGE

    // epilogue: unnormalized bf16 O^T partial + fp32 lsum partial
    float lsum = lsg + __shfl_xor(lsg, 32, 64);
    int b = bh >> 4, h = bh & 15;
    unsigned short* dst = Op + sp * (NTOK * DIM) + ((b * TT) + qrow) * DIM + h * HD + hi * 4;
#pragma unroll
    for (int mtd = 0; mtd < 2; mtd++) {
#pragma unroll
        for (int g4 = 0; g4 < 4; g4++) {
            us4 ov;
#pragma unroll
            for (int r = 0; r < 4; r++)
                ov[r] = f2bf(oacc[mtd][g4 * 4 + r]);   // dim = 32*mtd + 8*g4 + 4*hi + r
            *(us4*)&dst[mtd * 32 + g4 * 8] = ov;
        }
    }
    if (hi == 0)
        Ls[sp * 65536 + bh * 2048 + qrow] = lsum;
}

extern "C" void kernel_launch(void* const* d_in, const int* in_sizes, int n_in,
                              void* d_out, int out_size, void* d_ws, size_t ws_size,
                              hipStream_t stream) {
    const float* x  = (const float*)d_in[0];
    const float* Wq = (const float*)d_in[1];
    const float* Wk = (const float*)d_in[2];
    const float* Wv = (const float*)d_in[3];
    const float* Wo = (const float*)d_in[4];
    const float* bo = (const float*)d_in[5];
    float* out = (float*)d_out;
    char* ws = (char*)d_ws;

    // Op (16MB) aliases Xb+Wqkvt: both are dead after k_gemm_qkv, flash writes Op after.
    unsigned short* Xb    = (unsigned short*)(ws);                 //  8 MB
    unsigned short* Wqkvt = (unsigned short*)(ws + 8388608);       //  6 MB
    unsigned short* Op    = (unsigned short*)(ws);                 // 16 MB (aliases Xb/Wqkvt)
    unsigned short* QK    = (unsigned short*)(ws + 16777216);      // 16 MB (Q then K)
    unsigned short* Vt    = (unsigned short*)(ws + 33554432);      //  8 MB (V transposed)
    unsigned short* Wo2t  = (unsigned short*)(ws + 50331648);      //  2 MB
    float*          rope  = (float*)(ws + 52428800);               // 512 KB
    float*          Rm    = (float*)(ws + 52953088);               // 16 KB
    float*          Ls    = (float*)(ws + 52969472);               // 512 KB

    hipLaunchKernelGGL(k_prep,     dim3(7680),   dim3(256), 0, stream, x, Xb, Wq, Wk, Wv, Wqkvt, rope);
    hipLaunchKernelGGL(k_R,        dim3(64),     dim3(256), 0, stream, rope, Rm);
    hipLaunchKernelGGL(k_wo2,      dim3(16, 16), dim3(256), 0, stream, Wo, Rm, Wo2t);
    hipLaunchKernelGGL(k_gemm_qkv, dim3(24, 32), dim3(256), 0, stream, Xb, Wqkvt, QK, Vt);
    hipLaunchKernelGGL(k_flash,    dim3(1024),   dim3(256), 0, stream, QK, Vt, Op, Ls);
    hipLaunchKernelGGL(k_gemm_out, dim3(8, 32),  dim3(256), 0, stream, Op, Ls, Wo2t, bo, out);
}

// Round 8
// 229.256 us; speedup vs baseline: 1.0005x; 1.0005x over previous
//
#include <hip/hip_runtime.h>
#include <math.h>

#define DIM 1024
#define NH 16
#define HD 64
#define TT 2048
#define NTOK 4096   // B*T

typedef __bf16 bf8v __attribute__((ext_vector_type(8)));
typedef float f4v __attribute__((ext_vector_type(4)));
typedef float f16v __attribute__((ext_vector_type(16)));
typedef unsigned short us8 __attribute__((ext_vector_type(8)));
typedef unsigned short us4 __attribute__((ext_vector_type(4)));
typedef unsigned int u4v __attribute__((ext_vector_type(4)));

static __device__ __forceinline__ unsigned short f2bf(float f) {
    unsigned int u = __float_as_uint(f);
    u += 0x7FFFu + ((u >> 16) & 1u);   // RNE
    return (unsigned short)(u >> 16);
}
static __device__ __forceinline__ bf8v ld8(const unsigned short* p) {
    return __builtin_bit_cast(bf8v, *(const us8*)p);
}
// async global->LDS, 16B per lane; HW dest = wave-uniform base + lane*16
static __device__ __forceinline__ void gl_lds(const unsigned short* g, unsigned short* l) {
    __builtin_amdgcn_global_load_lds((const __attribute__((address_space(1))) unsigned int*)(g),
                                     (__attribute__((address_space(3))) unsigned int*)(l), 16, 0, 0);
}

// ---------- fused prep: x->bf16 | W transpose->bf16 | rope table ----------
__global__ void k_prep(const float* __restrict__ x, unsigned short* __restrict__ xb,
                       const float* __restrict__ Wq, const float* __restrict__ Wk,
                       const float* __restrict__ Wv, unsigned short* __restrict__ wt,
                       float* __restrict__ rope) {
    int tid = threadIdx.x;
    int bb = blockIdx.x;
    if (bb < 4096) {                       // cast x (4 floats/thread)
        int i = bb * 256 + tid;
        float4 v = ((const float4*)x)[i];
        us4 o;
        o[0] = f2bf(v.x); o[1] = f2bf(v.y); o[2] = f2bf(v.z); o[3] = f2bf(v.w);
        *(us4*)&xb[i * 4] = o;
    } else if (bb < 7168) {                // transpose Wq|Wk|Wv
        __shared__ float tile[32][33];
        bb -= 4096;
        int z = bb >> 10, rem = bb & 1023;
        int bx = rem & 31, by = rem >> 5;
        const float* W = (z == 0) ? Wq : ((z == 1) ? Wk : Wv);
        int tx = tid & 31, ty = tid >> 5;   // (32, 8)
        int c0 = bx * 32, k0 = by * 32;
#pragma unroll
        for (int j = 0; j < 4; j++)
            tile[ty + j * 8][tx] = W[(k0 + ty + j * 8) * DIM + c0 + tx];
        __syncthreads();
        unsigned short* out = wt + z * DIM * DIM;
#pragma unroll
        for (int j = 0; j < 4; j++)
            out[(c0 + ty + j * 8) * DIM + k0 + tx] = f2bf(tile[tx][ty + j * 8]);
    } else {                               // rope [TT][HD]
        int i = (bb - 7168) * 256 + tid;
        int s = i >> 6, d = i & 63;
        float inv = exp2f(-(float)(d & 31) * (13.287712379549449f / 32.0f));
        float a = (float)s * inv;
        rope[i] = (d < 32) ? cosf(a) : sinf(a);
    }
}

// ---------------- R = rope^T rope (64x64), s-parallel x4 ----------------
__global__ void k_R(const float* __restrict__ rope, float* __restrict__ R) {
    __shared__ float red[256];
    int d = blockIdx.x;
    int e = threadIdx.x & 63, sl = threadIdx.x >> 6;
    const float* rp = rope + sl * 512 * 64;
    float acc = 0.f;
    for (int s = 0; s < 512; s++)
        acc += rp[s * 64 + d] * rp[s * 64 + e];
    red[threadIdx.x] = acc;
    __syncthreads();
    if (sl == 0)
        R[d * 64 + e] = (red[e] + red[e + 64]) + (red[e + 128] + red[e + 192]);
}

// ------------- Wo2t[j][r] = sum_e R[d][e] * Wo[h*64+e][j],  r = h*64+d -------------
__global__ void k_wo2(const float* __restrict__ Wo, const float* __restrict__ R,
                      unsigned short* __restrict__ wo2t) {
    __shared__ float Ws[64 * 65];   // Ws[e][j]
    __shared__ float Rt[64 * 65];   // Rt[e][d] = R[d*64+e]
    int tid = threadIdx.x;
    int h = blockIdx.y, j0 = blockIdx.x * 64;
    for (int idx = tid; idx < 4096; idx += 256) {
        int e = idx >> 6, j = idx & 63;
        Ws[e * 65 + j] = Wo[(h * 64 + e) * DIM + j0 + j];
        Rt[e * 65 + j] = R[j * 64 + e];
    }
    __syncthreads();
    int d = tid & 63, jb = (tid >> 6) * 16;
    float acc[16] = {};
    for (int e = 0; e < 64; e++) {
        float r = Rt[e * 65 + d];
#pragma unroll
        for (int jj = 0; jj < 16; jj++)
            acc[jj] += r * Ws[e * 65 + jb + jj];
    }
#pragma unroll
    for (int jj = 0; jj < 16; jj++)
        wo2t[(j0 + jb + jj) * DIM + h * 64 + d] = f2bf(acc[jj]);
}

// ================= GEMM core (m97-style): global_load_lds staging, XOR-swizzled LDS =================
// LDS layout: row-major [128][32] bf16, but 16B chunk q of row r stored at phys slot q^(r&3).
// Frag read for logical quarter `quad` uses qx = quad^(l16&3) -> bank-uniform (no >2-way conflicts).

// QKV projection: N = 3072. Q (pre-scaled by c1), K scatter to [B][H][T][64];
// V TRANSPOSED to [B][H][64][T].
__global__ __launch_bounds__(256, 3) void k_gemm_qkv(const unsigned short* __restrict__ A,
                                                     const unsigned short* __restrict__ Bt,
                                                     unsigned short* __restrict__ qk,
                                                     unsigned short* __restrict__ vt) {
    __shared__ unsigned short As[128 * 32];
    __shared__ unsigned short Bs[128 * 32];
    const int K = 1024;
    int tid = threadIdx.x;
    int lane = tid & 63, w = tid >> 6;
    int quad = lane >> 4, l16 = lane & 15;
    int m0 = blockIdx.y * 128, n0 = blockIdx.x * 128;
    int wm = (w >> 1) * 64, wn = (w & 1) * 64;

    // two 16B staging chunks per thread, lane-contiguous per wave
    int s0 = tid, s1 = 256 + tid;
    int r0 = s0 >> 2, cc0 = ((s0 & 3) ^ (r0 & 3)) * 8;
    int r1 = s1 >> 2, cc1 = ((s1 & 3) ^ (r1 & 3)) * 8;
    const unsigned short* Ag0 = A + (m0 + r0) * K + cc0;
    const unsigned short* Ag1 = A + (m0 + r1) * K + cc1;
    const unsigned short* Bg0 = Bt + (n0 + r0) * K + cc0;
    const unsigned short* Bg1 = Bt + (n0 + r1) * K + cc1;
    int qx = quad ^ (l16 & 3);

    f4v acc[4][4] = {};
    for (int k0 = 0; k0 < K; k0 += 32) {
        __syncthreads();                       // prior iter frag reads done
        gl_lds(Ag0 + k0, &As[s0 * 8]);
        gl_lds(Ag1 + k0, &As[s1 * 8]);
        gl_lds(Bg0 + k0, &Bs[s0 * 8]);
        gl_lds(Bg1 + k0, &Bs[s1 * 8]);
        __syncthreads();                       // drains vmcnt -> tiles in LDS
        bf8v af[4], bf[4];
#pragma unroll
        for (int mt = 0; mt < 4; mt++)
            af[mt] = ld8(&As[(wm + mt * 16 + l16) * 32 + qx * 8]);
#pragma unroll
        for (int nt = 0; nt < 4; nt++)
            bf[nt] = ld8(&Bs[(wn + nt * 16 + l16) * 32 + qx * 8]);
#pragma unroll
        for (int mt = 0; mt < 4; mt++)
#pragma unroll
            for (int nt = 0; nt < 4; nt++)
                acc[mt][nt] = __builtin_amdgcn_mfma_f32_16x16x32_bf16(af[mt], bf[nt], acc[mt][nt], 0, 0, 0);
    }
#pragma unroll
    for (int mt = 0; mt < 4; mt++) {
#pragma unroll
        for (int nt = 0; nt < 4; nt++) {
            int gc = n0 + wn + nt * 16 + l16;
            int h = (gc >> 6) & 15;
            int d = gc & 63;
            if (gc < 2048) {             // Q or K: [mtx][B][H][T][64]; Q pre-scaled by c1
                float qs = (gc < 1024) ? 0.18033688011111793f : 1.0f;
                int mtx = gc >> 10;
                unsigned short* base = qk + mtx * (NTOK * DIM);
#pragma unroll
                for (int r = 0; r < 4; r++) {
                    int gm = m0 + wm + mt * 16 + quad * 4 + r;
                    int b = gm >> 11, t = gm & 2047;
                    base[((b * NH + h) * TT + t) * HD + d] = f2bf(acc[mt][nt][r] * qs);
                }
            } else {                     // V: transposed [B][H][64][T]
                int gm0 = m0 + wm + mt * 16 + quad * 4;
                int b = gm0 >> 11, t = gm0 & 2047;
                us4 ov;
#pragma unroll
                for (int r = 0; r < 4; r++)
                    ov[r] = f2bf(acc[mt][nt][r]);
                *(us4*)&vt[(((b * NH + h) * HD) + d) * TT + t] = ov;
            }
        }
    }
}

// Output projection with FUSED COMBINE (pipelined): A = (Op0+Op1)*inv(token,head) built
// in-register during staging. A/Ls data for iter i+1 is PREFETCHED after iter i's second
// barrier -> L2 latency hides under the frag-read+MFMA phase and drains at next barrier-1
// vmcnt(0). Pure code motion vs round-7 (both __syncthreads retained).
__global__ __launch_bounds__(256, 3) void k_gemm_out(const unsigned short* __restrict__ Op,
                                                     const float* __restrict__ Ls,
                                                     const unsigned short* __restrict__ Bt,
                                                     const float* __restrict__ bo,
                                                     float* __restrict__ out) {
    __shared__ unsigned short As[128 * 32];
    __shared__ unsigned short Bs[128 * 32];
    const int K = 1024;
    int tid = threadIdx.x;
    int lane = tid & 63, w = tid >> 6;
    int quad = lane >> 4, l16 = lane & 15;
    int m0 = blockIdx.y * 128, n0 = blockIdx.x * 128;
    int wm = (w >> 1) * 64, wn = (w & 1) * 64;

    int s0 = tid, s1 = 256 + tid;
    int r0 = s0 >> 2, cc0 = ((s0 & 3) ^ (r0 & 3)) * 8;
    int r1 = s1 >> 2, cc1 = ((s1 & 3) ^ (r1 & 3)) * 8;
    int gm0 = m0 + r0, gm1 = m0 + r1;
    const unsigned short* Ag0 = Op + gm0 * K + cc0;
    const unsigned short* Ag1 = Op + gm1 * K + cc1;
    const unsigned short* Bg0 = Bt + (n0 + r0) * K + cc0;
    const unsigned short* Bg1 = Bt + (n0 + r1) * K + cc1;
    // Ls[sp*65536 + (b*16+h)*2048 + t]; per-thread t,b fixed; h varies with k0
    const float* L0 = Ls + (gm0 >> 11) * 16 * 2048 + (gm0 & 2047);
    const float* L1 = Ls + (gm1 >> 11) * 16 * 2048 + (gm1 & 2047);
    int qx = quad ^ (l16 & 3);

    // prologue prefetch for k0 = 0 (h0 = cc>>6 = 0)
    us8 pa0 = *(const us8*)(Ag0);
    us8 pc0 = *(const us8*)(Ag0 + NTOK * DIM);
    us8 pa1 = *(const us8*)(Ag1);
    us8 pc1 = *(const us8*)(Ag1 + NTOK * DIM);
    float pl00 = L0[0], pl01 = L0[65536];
    float pl10 = L1[0], pl11 = L1[65536];

    f4v acc[4][4] = {};
    for (int k0 = 0; k0 < K; k0 += 32) {
        __syncthreads();                       // prior iter frag reads done; drains prefetch loads
        gl_lds(Bg0 + k0, &Bs[s0 * 8]);
        gl_lds(Bg1 + k0, &Bs[s1 * 8]);
        {
            float inv0 = __builtin_amdgcn_rcpf(pl00 + pl01);
            float inv1 = __builtin_amdgcn_rcpf(pl10 + pl11);
            u4v o0, o1;
#pragma unroll
            for (int p = 0; p < 4; p++) {
                float va = (__uint_as_float((unsigned int)pa0[2 * p] << 16) +
                            __uint_as_float((unsigned int)pc0[2 * p] << 16)) * inv0;
                float vb = (__uint_as_float((unsigned int)pa0[2 * p + 1] << 16) +
                            __uint_as_float((unsigned int)pc0[2 * p + 1] << 16)) * inv0;
                unsigned int wd;
                asm("v_cvt_pk_bf16_f32 %0, %1, %2" : "=v"(wd) : "v"(va), "v"(vb));
                o0[p] = wd;
                float vc = (__uint_as_float((unsigned int)pa1[2 * p] << 16) +
                            __uint_as_float((unsigned int)pc1[2 * p] << 16)) * inv1;
                float vd = (__uint_as_float((unsigned int)pa1[2 * p + 1] << 16) +
                            __uint_as_float((unsigned int)pc1[2 * p + 1] << 16)) * inv1;
                asm("v_cvt_pk_bf16_f32 %0, %1, %2" : "=v"(wd) : "v"(vc), "v"(vd));
                o1[p] = wd;
            }
            *(u4v*)&As[s0 * 8] = o0;           // ds_write_b128
            *(u4v*)&As[s1 * 8] = o1;
        }
        __syncthreads();                       // drains vmcnt (gl_lds) + lgkm (ds_write)
        // ---- prefetch A/Ls for next iter: hides under frag reads + MFMA ----
        {
            int kn = (k0 + 32) & 1023;         // last iter wraps (harmless redundant load)
            int h0n = (kn + cc0) >> 6, h1n = (kn + cc1) >> 6;
            pa0 = *(const us8*)(Ag0 + kn);
            pc0 = *(const us8*)(Ag0 + NTOK * DIM + kn);
            pa1 = *(const us8*)(Ag1 + kn);
            pc1 = *(const us8*)(Ag1 + NTOK * DIM + kn);
            pl00 = L0[h0n * 2048]; pl01 = L0[65536 + h0n * 2048];
            pl10 = L1[h1n * 2048]; pl11 = L1[65536 + h1n * 2048];
        }
        bf8v af[4], bf[4];
#pragma unroll
        for (int mt = 0; mt < 4; mt++)
            af[mt] = ld8(&As[(wm + mt * 16 + l16) * 32 + qx * 8]);
#pragma unroll
        for (int nt = 0; nt < 4; nt++)
            bf[nt] = ld8(&Bs[(wn + nt * 16 + l16) * 32 + qx * 8]);
#pragma unroll
        for (int mt = 0; mt < 4; mt++)
#pragma unroll
            for (int nt = 0; nt < 4; nt++)
                acc[mt][nt] = __builtin_amdgcn_mfma_f32_16x16x32_bf16(af[mt], bf[nt], acc[mt][nt], 0, 0, 0);
    }
#pragma unroll
    for (int mt = 0; mt < 4; mt++) {
#pragma unroll
        for (int nt = 0; nt < 4; nt++) {
            int gc = n0 + wn + nt * 16 + l16;
            float bias = bo[gc];
#pragma unroll
            for (int r = 0; r < 4; r++) {
                int gm = m0 + wm + mt * 16 + quad * 4 + r;
                out[gm * DIM + gc] = acc[mt][nt][r] + bias;
            }
        }
    }
}

// ================= flash attention v4 (round-4 proven): 4 blocks/CU, chunk-fused =================
// grid 1024, 256 thr, 32 q-rows/wave. Each SIMD hosts waves from different blocks -> cross-block
// MFMA/VALU overlap. Per 16-key chunk, softmax pack feeds its 2 PV MFMAs immediately.
// Staging: swizzled global source + linear LDS dest (involution p^=(r&7)); dbuf, counted vmcnt(4).
__global__ __launch_bounds__(256, 4) void k_flash(const unsigned short* __restrict__ qk,
                                                  const unsigned short* __restrict__ vt,
                                                  unsigned short* __restrict__ Op,
                                                  float* __restrict__ Ls) {
    __shared__ unsigned short Ks[2][64 * 64];
    __shared__ unsigned short Vs[2][64 * 64];
    int tid = threadIdx.x;
    int lane = tid & 63, w = tid >> 6;
    int q31 = lane & 31, hi = lane >> 5;
    int bid = blockIdx.x;
    int xcd = bid & 7, sl = bid >> 3;
    int bh = xcd * 4 + (sl & 3);
    int qt = (sl >> 2) & 15;
    int sp = sl >> 6;

    const unsigned short* Qg = qk + bh * (TT * HD);
    const unsigned short* Kg = qk + NTOK * DIM + bh * (TT * HD) + sp * 1024 * HD;
    const unsigned short* Vg = vt + bh * (HD * TT) + sp * 1024;

    // Q B-frag (k=dim): lane n=q31 holds Q[qrow][16*ks + 8*hi + j]
    int qrow = qt * 128 + w * 32 + q31;
    bf8v qf[4];
#pragma unroll
    for (int ks = 0; ks < 4; ks++)
        qf[ks] = ld8(Qg + qrow * HD + ks * 16 + hi * 8);

    // staging: 512 chunks of 16B per tile; thread stages chunks tid and 256+tid.
    // chunk idx -> row r=idx>>3, phys slot p=idx&7, logical chunk c=p^(r&7) (involution).
    int r0 = tid >> 3, sw = (tid & 7) ^ (r0 & 7);
    int offK0 = r0 * HD + sw * 8, offK1 = offK0 + 32 * HD;
    int offV0 = r0 * TT + sw * 8, offV1 = offV0 + 32 * TT;
    int dst0 = tid * 8, dst1 = dst0 + 2048;

#define STAGE(tile, bufsel) do {                                  \
        const unsigned short* kb_ = Kg + (tile) * 64 * HD;        \
        const unsigned short* vb_ = Vg + (tile) * 64;             \
        gl_lds(kb_ + offK0, &Ks[bufsel][dst0]);                   \
        gl_lds(kb_ + offK1, &Ks[bufsel][dst1]);                   \
        gl_lds(vb_ + offV0, &Vs[bufsel][dst0]);                   \
        gl_lds(vb_ + offV1, &Vs[bufsel][dst1]);                   \
    } while (0)

    STAGE(0, 0);
    STAGE(1, 1);

    f16v oacc[2] = {};               // [mtd] O^T dim tiles
    float lsg = 0.f;
    int xsw = q31 & 7;

    for (int it = 0; it < 16; it++) {
        int cur = it & 1;
        if (it == 15) { asm volatile("s_waitcnt vmcnt(0)" ::: "memory"); }
        else          { asm volatile("s_waitcnt vmcnt(4)" ::: "memory"); }
        __builtin_amdgcn_s_barrier();
        asm volatile("" ::: "memory");

        const unsigned short* Kb = Ks[cur];
        const unsigned short* Vb = Vs[cur];

        // K frags + QK^T: S^T[key][qrow], 2 key tiles x K=64 (4 steps)
        bf8v kf0[4], kf1[4];
#pragma unroll
        for (int ks = 0; ks < 4; ks++) {
            kf0[ks] = ld8(&Kb[(q31) * 64 + ((2 * ks + hi) ^ xsw) * 8]);
            kf1[ks] = ld8(&Kb[(32 + q31) * 64 + ((2 * ks + hi) ^ xsw) * 8]);
        }
        f16v s0 = {}, s1 = {};
#pragma unroll
        for (int ks = 0; ks < 4; ks++) {
            s0 = __builtin_amdgcn_mfma_f32_32x32x16_bf16(kf0[ks], qf[ks], s0, 0, 0, 0);
            s1 = __builtin_amdgcn_mfma_f32_32x32x16_bf16(kf1[ks], qf[ks], s1, 0, 0, 0);
        }

        // V^T A-frags (ds_read latency hides under softmax chunks)
        bf8v vf[2][4];
#pragma unroll
        for (int kk = 0; kk < 4; kk++) {
            vf[0][kk] = ld8(&Vb[(q31) * 64 + ((2 * kk + hi) ^ xsw) * 8]);
            vf[1][kk] = ld8(&Vb[(32 + q31) * 64 + ((2 * kk + hi) ^ xsw) * 8]);
        }

        // chunk-fused softmax -> PV. Per 16-key chunk kk = mt*2+sub:
        // reg r of s_mt holds S^T[key = 32mt + (r&3)+8(r>>2)+4hi][qrow]; p = 2^s (Q pre-scaled).
        // cvt_pk pairs -> e0..e3 (keys {0,1},{2,3},{8,9},{10,11}+4hi); swap(e0,e2)+swap(e1,e3)
        // -> P^T B-frag words (k=8hi+j). Then 2 PV MFMAs for this chunk overlap next chunk VALU.
#pragma unroll
        for (int mt = 0; mt < 2; mt++) {
#pragma unroll
            for (int sub = 0; sub < 2; sub++) {
                const f16v& s = mt ? s1 : s0;
                float pe[8];
#pragma unroll
                for (int j = 0; j < 8; j++)
                    pe[j] = __builtin_amdgcn_exp2f(s[sub * 8 + j]);
                float t01 = pe[0] + pe[1], t23 = pe[2] + pe[3];
                float t45 = pe[4] + pe[5], t67 = pe[6] + pe[7];
                lsg += (t01 + t23) + (t45 + t67);
                unsigned int e0, e1, e2, e3;
                asm("v_cvt_pk_bf16_f32 %0, %1, %2" : "=v"(e0) : "v"(pe[0]), "v"(pe[1]));
                asm("v_cvt_pk_bf16_f32 %0, %1, %2" : "=v"(e1) : "v"(pe[2]), "v"(pe[3]));
                asm("v_cvt_pk_bf16_f32 %0, %1, %2" : "=v"(e2) : "v"(pe[4]), "v"(pe[5]));
                asm("v_cvt_pk_bf16_f32 %0, %1, %2" : "=v"(e3) : "v"(pe[6]), "v"(pe[7]));
                asm("v_permlane32_swap_b32 %0, %1" : "+v"(e0), "+v"(e2));
                asm("v_permlane32_swap_b32 %0, %1" : "+v"(e1), "+v"(e3));
                u4v pv = {e0, e1, e2, e3};
                bf8v pb = __builtin_bit_cast(bf8v, pv);
                int kk = mt * 2 + sub;
                oacc[0] = __builtin_amdgcn_mfma_f32_32x32x16_bf16(vf[0][kk], pb, oacc[0], 0, 0, 0);
                oacc[1] = __builtin_amdgcn_mfma_f32_32x32x16_bf16(vf[1][kk], pb, oacc[1], 0, 0, 0);
            }
        }

        __builtin_amdgcn_s_barrier();
        asm volatile("" ::: "memory");
        if (it < 14) STAGE(it + 2, cur);
    }
#undef STAGE

    // epilogue: unnormalized bf16 O^T partial + fp32 lsum partial
    float lsum = lsg + __shfl_xor(lsg, 32, 64);
    int b = bh >> 4, h = bh & 15;
    unsigned short* dst = Op + sp * (NTOK * DIM) + ((b * TT) + qrow) * DIM + h * HD + hi * 4;
#pragma unroll
    for (int mtd = 0; mtd < 2; mtd++) {
#pragma unroll
        for (int g4 = 0; g4 < 4; g4++) {
            us4 ov;
#pragma unroll
            for (int r = 0; r < 4; r++)
                ov[r] = f2bf(oacc[mtd][g4 * 4 + r]);   // dim = 32*mtd + 8*g4 + 4*hi + r
            *(us4*)&dst[mtd * 32 + g4 * 8] = ov;
        }
    }
    if (hi == 0)
        Ls[sp * 65536 + bh * 2048 + qrow] = lsum;
}

extern "C" void kernel_launch(void* const* d_in, const int* in_sizes, int n_in,
                              void* d_out, int out_size, void* d_ws, size_t ws_size,
                              hipStream_t stream) {
    const float* x  = (const float*)d_in[0];
    const float* Wq = (const float*)d_in[1];
    const float* Wk = (const float*)d_in[2];
    const float* Wv = (const float*)d_in[3];
    const float* Wo = (const float*)d_in[4];
    const float* bo = (const float*)d_in[5];
    float* out = (float*)d_out;
    char* ws = (char*)d_ws;

    // Op (16MB) aliases Xb+Wqkvt: both are dead after k_gemm_qkv, flash writes Op after.
    unsigned short* Xb    = (unsigned short*)(ws);                 //  8 MB
    unsigned short* Wqkvt = (unsigned short*)(ws + 8388608);       //  6 MB
    unsigned short* Op    = (unsigned short*)(ws);                 // 16 MB (aliases Xb/Wqkvt)
    unsigned short* QK    = (unsigned short*)(ws + 16777216);      // 16 MB (Q then K)
    unsigned short* Vt    = (unsigned short*)(ws + 33554432);      //  8 MB (V transposed)
    unsigned short* Wo2t  = (unsigned short*)(ws + 50331648);      //  2 MB
    float*          rope  = (float*)(ws + 52428800);               // 512 KB
    float*          Rm    = (float*)(ws + 52953088);               // 16 KB
    float*          Ls    = (float*)(ws + 52969472);               // 512 KB

    hipLaunchKernelGGL(k_prep,     dim3(7680),   dim3(256), 0, stream, x, Xb, Wq, Wk, Wv, Wqkvt, rope);
    hipLaunchKernelGGL(k_R,        dim3(64),     dim3(256), 0, stream, rope, Rm);
    hipLaunchKernelGGL(k_wo2,      dim3(16, 16), dim3(256), 0, stream, Wo, Rm, Wo2t);
    hipLaunchKernelGGL(k_gemm_qkv, dim3(24, 32), dim3(256), 0, stream, Xb, Wqkvt, QK, Vt);
    hipLaunchKernelGGL(k_flash,    dim3(1024),   dim3(256), 0, stream, QK, Vt, Op, Ls);
    hipLaunchKernelGGL(k_gemm_out, dim3(8, 32),  dim3(256), 0, stream, Op, Ls, Wo2t, bo, out);
}

// Round 9
// 202.794 us; speedup vs baseline: 1.1311x; 1.1305x over previous
//
#include <hip/hip_runtime.h>
#include <math.h>

#define DIM 1024
#define NH 16
#define HD 64
#define TT 2048
#define NTOK 4096   // B*T

typedef __bf16 bf8v __attribute__((ext_vector_type(8)));
typedef float f4v __attribute__((ext_vector_type(4)));
typedef float f16v __attribute__((ext_vector_type(16)));
typedef unsigned short us8 __attribute__((ext_vector_type(8)));
typedef unsigned short us4 __attribute__((ext_vector_type(4)));
typedef unsigned int u4v __attribute__((ext_vector_type(4)));

static __device__ __forceinline__ unsigned short f2bf(float f) {
    unsigned int u = __float_as_uint(f);
    u += 0x7FFFu + ((u >> 16) & 1u);   // RNE
    return (unsigned short)(u >> 16);
}
static __device__ __forceinline__ bf8v ld8(const unsigned short* p) {
    return __builtin_bit_cast(bf8v, *(const us8*)p);
}
// async global->LDS, 16B per lane; HW dest = wave-uniform base + lane*16
static __device__ __forceinline__ void gl_lds(const unsigned short* g, unsigned short* l) {
    __builtin_amdgcn_global_load_lds((const __attribute__((address_space(1))) unsigned int*)(g),
                                     (__attribute__((address_space(3))) unsigned int*)(l), 16, 0, 0);
}

// ---------- fused prep: x->bf16 | W transpose->bf16 | rope table | zero Rm ----------
__global__ void k_prep(const float* __restrict__ x, unsigned short* __restrict__ xb,
                       const float* __restrict__ Wq, const float* __restrict__ Wk,
                       const float* __restrict__ Wv, unsigned short* __restrict__ wt,
                       float* __restrict__ rope, float* __restrict__ Rm) {
    int tid = threadIdx.x;
    int bb = blockIdx.x;
    if (bb < 4096) {                       // cast x (4 floats/thread)
        int i = bb * 256 + tid;
        float4 v = ((const float4*)x)[i];
        us4 o;
        o[0] = f2bf(v.x); o[1] = f2bf(v.y); o[2] = f2bf(v.z); o[3] = f2bf(v.w);
        *(us4*)&xb[i * 4] = o;
    } else if (bb < 7168) {                // transpose Wq|Wk|Wv
        __shared__ float tile[32][33];
        bb -= 4096;
        int z = bb >> 10, rem = bb & 1023;
        int bx = rem & 31, by = rem >> 5;
        const float* W = (z == 0) ? Wq : ((z == 1) ? Wk : Wv);
        int tx = tid & 31, ty = tid >> 5;   // (32, 8)
        int c0 = bx * 32, k0 = by * 32;
#pragma unroll
        for (int j = 0; j < 4; j++)
            tile[ty + j * 8][tx] = W[(k0 + ty + j * 8) * DIM + c0 + tx];
        __syncthreads();
        unsigned short* out = wt + z * DIM * DIM;
#pragma unroll
        for (int j = 0; j < 4; j++)
            out[(c0 + ty + j * 8) * DIM + k0 + tx] = f2bf(tile[tx][ty + j * 8]);
    } else if (bb < 7680) {                // rope [TT][HD]
        int i = (bb - 7168) * 256 + tid;
        int s = i >> 6, d = i & 63;
        float inv = exp2f(-(float)(d & 31) * (13.287712379549449f / 32.0f));
        float a = (float)s * inv;
        rope[i] = (d < 32) ? cosf(a) : sinf(a);
    } else {                               // zero Rm (4096 floats) for k_R atomics
        Rm[(bb - 7680) * 256 + tid] = 0.f;
    }
}

// ---------------- R = rope^T rope (64x64), 8x s-parallel blocks, atomic partials ----------------
__global__ void k_R(const float* __restrict__ rope, float* __restrict__ R) {
    __shared__ float red[256];
    int d = blockIdx.x & 63, sg = blockIdx.x >> 6;    // 64 d x 8 s-groups
    int e = threadIdx.x & 63, sl = threadIdx.x >> 6;
    const float* rp = rope + (sg * 256 + sl * 64) * 64;
    float acc = 0.f;
    for (int s = 0; s < 64; s++)
        acc += rp[s * 64 + d] * rp[s * 64 + e];
    red[threadIdx.x] = acc;
    __syncthreads();
    if (sl == 0)
        atomicAdd(&R[d * 64 + e], (red[e] + red[e + 64]) + (red[e + 128] + red[e + 192]));
}

// ------------- Wo2t[j][r] = sum_e R[d][e] * Wo[h*64+e][j],  r = h*64+d -------------
__global__ void k_wo2(const float* __restrict__ Wo, const float* __restrict__ R,
                      unsigned short* __restrict__ wo2t) {
    __shared__ float Ws[64 * 65];   // Ws[e][j]
    __shared__ float Rt[64 * 65];   // Rt[e][d] = R[d*64+e]
    int tid = threadIdx.x;
    int h = blockIdx.y, j0 = blockIdx.x * 64;
    for (int idx = tid; idx < 4096; idx += 256) {
        int e = idx >> 6, j = idx & 63;
        Ws[e * 65 + j] = Wo[(h * 64 + e) * DIM + j0 + j];
        Rt[e * 65 + j] = R[j * 64 + e];
    }
    __syncthreads();
    int d = tid & 63, jb = (tid >> 6) * 16;
    float acc[16] = {};
    for (int e = 0; e < 64; e++) {
        float r = Rt[e * 65 + d];
#pragma unroll
        for (int jj = 0; jj < 16; jj++)
            acc[jj] += r * Ws[e * 65 + jb + jj];
    }
#pragma unroll
    for (int jj = 0; jj < 16; jj++)
        wo2t[(j0 + jb + jj) * DIM + h * 64 + d] = f2bf(acc[jj]);
}

// ================= GEMM core (m97-style): global_load_lds staging, XOR-swizzled LDS =================
// LDS layout: row-major [*][32] bf16, 16B chunk q of row r stored at phys slot q^(r&3).
// Frag read for logical quarter `quad` uses qx = quad^(l16&3) -> bank-uniform.

// QKV projection: N = 3072. Q (pre-scaled by c1), K scatter to [B][H][T][64];
// V TRANSPOSED to [B][H][64][T].
__global__ __launch_bounds__(256, 3) void k_gemm_qkv(const unsigned short* __restrict__ A,
                                                     const unsigned short* __restrict__ Bt,
                                                     unsigned short* __restrict__ qk,
                                                     unsigned short* __restrict__ vt) {
    __shared__ unsigned short As[128 * 32];
    __shared__ unsigned short Bs[128 * 32];
    const int K = 1024;
    int tid = threadIdx.x;
    int lane = tid & 63, w = tid >> 6;
    int quad = lane >> 4, l16 = lane & 15;
    int m0 = blockIdx.y * 128, n0 = blockIdx.x * 128;
    int wm = (w >> 1) * 64, wn = (w & 1) * 64;

    // two 16B staging chunks per thread, lane-contiguous per wave
    int s0 = tid, s1 = 256 + tid;
    int r0 = s0 >> 2, cc0 = ((s0 & 3) ^ (r0 & 3)) * 8;
    int r1 = s1 >> 2, cc1 = ((s1 & 3) ^ (r1 & 3)) * 8;
    const unsigned short* Ag0 = A + (m0 + r0) * K + cc0;
    const unsigned short* Ag1 = A + (m0 + r1) * K + cc1;
    const unsigned short* Bg0 = Bt + (n0 + r0) * K + cc0;
    const unsigned short* Bg1 = Bt + (n0 + r1) * K + cc1;
    int qx = quad ^ (l16 & 3);

    f4v acc[4][4] = {};
    for (int k0 = 0; k0 < K; k0 += 32) {
        __syncthreads();                       // prior iter frag reads done
        gl_lds(Ag0 + k0, &As[s0 * 8]);
        gl_lds(Ag1 + k0, &As[s1 * 8]);
        gl_lds(Bg0 + k0, &Bs[s0 * 8]);
        gl_lds(Bg1 + k0, &Bs[s1 * 8]);
        __syncthreads();                       // drains vmcnt -> tiles in LDS
        bf8v af[4], bf[4];
#pragma unroll
        for (int mt = 0; mt < 4; mt++)
            af[mt] = ld8(&As[(wm + mt * 16 + l16) * 32 + qx * 8]);
#pragma unroll
        for (int nt = 0; nt < 4; nt++)
            bf[nt] = ld8(&Bs[(wn + nt * 16 + l16) * 32 + qx * 8]);
#pragma unroll
        for (int mt = 0; mt < 4; mt++)
#pragma unroll
            for (int nt = 0; nt < 4; nt++)
                acc[mt][nt] = __builtin_amdgcn_mfma_f32_16x16x32_bf16(af[mt], bf[nt], acc[mt][nt], 0, 0, 0);
    }
#pragma unroll
    for (int mt = 0; mt < 4; mt++) {
#pragma unroll
        for (int nt = 0; nt < 4; nt++) {
            int gc = n0 + wn + nt * 16 + l16;
            int h = (gc >> 6) & 15;
            int d = gc & 63;
            if (gc < 2048) {             // Q or K: [mtx][B][H][T][64]; Q pre-scaled by c1
                float qs = (gc < 1024) ? 0.18033688011111793f : 1.0f;
                int mtx = gc >> 10;
                unsigned short* base = qk + mtx * (NTOK * DIM);
#pragma unroll
                for (int r = 0; r < 4; r++) {
                    int gm = m0 + wm + mt * 16 + quad * 4 + r;
                    int b = gm >> 11, t = gm & 2047;
                    base[((b * NH + h) * TT + t) * HD + d] = f2bf(acc[mt][nt][r] * qs);
                }
            } else {                     // V: transposed [B][H][64][T]
                int gm0 = m0 + wm + mt * 16 + quad * 4;
                int b = gm0 >> 11, t = gm0 & 2047;
                us4 ov;
#pragma unroll
                for (int r = 0; r < 4; r++)
                    ov[r] = f2bf(acc[mt][nt][r]);
                *(us4*)&vt[(((b * NH + h) * HD) + d) * TT + t] = ov;
            }
        }
    }
}

// Output projection v3: FUSED COMBINE + XCD-grouped + BM=64 (512 blocks, 2/CU).
// Decode: xcd=bid&7, slot=bid>>3; y = xcd*8 + (slot&7) (m-panel, 64 rows), x = slot>>3 (n-panel).
// -> each XCD owns 8 m-panels (2MB Op slice, L2-resident, fetched ~once); the 8 blocks per
// XCD sharing an n-panel reuse the B panel via L2. A = (Op0+Op1)*inv built in-register during
// staging (prefetched 1 iter ahead; L2-hit latency hides under MFMA phase).
__global__ __launch_bounds__(256, 2) void k_gemm_out(const unsigned short* __restrict__ Op,
                                                     const float* __restrict__ Ls,
                                                     const unsigned short* __restrict__ Bt,
                                                     const float* __restrict__ bo,
                                                     float* __restrict__ out) {
    __shared__ unsigned short As[64 * 32];
    __shared__ unsigned short Bs[128 * 32];
    const int K = 1024;
    int tid = threadIdx.x;
    int lane = tid & 63, w = tid >> 6;
    int quad = lane >> 4, l16 = lane & 15;
    int bid = blockIdx.x;
    int xcd = bid & 7, slot = bid >> 3;
    int y = xcd * 8 + (slot & 7);        // 0..63 m-panel
    int x = slot >> 3;                   // 0..7  n-panel
    int m0 = y * 64, n0 = x * 128;
    int wn = w * 32;                     // wave covers 64 rows x 32 cols

    // staging: rows 0..63 (A) / 0..127 (B), 4 chunks of 8 per 32-col row
    int rr = tid >> 2, cc = ((tid & 3) ^ (rr & 3)) * 8;
    int gm0 = m0 + rr;
    const unsigned short* Ag0 = Op + gm0 * K + cc;
    const unsigned short* Bg0 = Bt + (n0 + rr) * K + cc;
    const unsigned short* Bg1 = Bt + (n0 + 64 + rr) * K + cc;
    // Ls[sp*65536 + (b*16+h)*2048 + t]
    const float* L0 = Ls + (gm0 >> 11) * 16 * 2048 + (gm0 & 2047);
    int qx = quad ^ (l16 & 3);

    // prologue prefetch for k0 = 0
    us8 pa0 = *(const us8*)(Ag0);
    us8 pc0 = *(const us8*)(Ag0 + NTOK * DIM);
    float pl00 = L0[0], pl01 = L0[65536];

    f4v acc[4][2] = {};
    for (int k0 = 0; k0 < K; k0 += 32) {
        __syncthreads();                       // prior iter frag reads done; prefetch drained
        gl_lds(Bg0 + k0, &Bs[tid * 8]);
        gl_lds(Bg1 + k0, &Bs[(256 + tid) * 8]);
        {
            float inv0 = __builtin_amdgcn_rcpf(pl00 + pl01);
            u4v o0;
#pragma unroll
            for (int p = 0; p < 4; p++) {
                float va = (__uint_as_float((unsigned int)pa0[2 * p] << 16) +
                            __uint_as_float((unsigned int)pc0[2 * p] << 16)) * inv0;
                float vb = (__uint_as_float((unsigned int)pa0[2 * p + 1] << 16) +
                            __uint_as_float((unsigned int)pc0[2 * p + 1] << 16)) * inv0;
                unsigned int wd;
                asm("v_cvt_pk_bf16_f32 %0, %1, %2" : "=v"(wd) : "v"(va), "v"(vb));
                o0[p] = wd;
            }
            *(u4v*)&As[tid * 8] = o0;          // ds_write_b128
        }
        __syncthreads();                       // drains vmcnt (gl_lds) + lgkm (ds_write)
        // ---- prefetch A/Ls for next iter: L2-hit latency hides under frag reads + MFMA ----
        {
            int kn = (k0 + 32) & 1023;         // last iter wraps (harmless redundant load)
            int hn = (kn + cc) >> 6;
            pa0 = *(const us8*)(Ag0 + kn);
            pc0 = *(const us8*)(Ag0 + NTOK * DIM + kn);
            pl00 = L0[hn * 2048]; pl01 = L0[65536 + hn * 2048];
        }
        bf8v af[4], bf[2];
#pragma unroll
        for (int mt = 0; mt < 4; mt++)
            af[mt] = ld8(&As[(mt * 16 + l16) * 32 + qx * 8]);
#pragma unroll
        for (int nt = 0; nt < 2; nt++)
            bf[nt] = ld8(&Bs[(wn + nt * 16 + l16) * 32 + qx * 8]);
#pragma unroll
        for (int mt = 0; mt < 4; mt++)
#pragma unroll
            for (int nt = 0; nt < 2; nt++)
                acc[mt][nt] = __builtin_amdgcn_mfma_f32_16x16x32_bf16(af[mt], bf[nt], acc[mt][nt], 0, 0, 0);
    }
#pragma unroll
    for (int mt = 0; mt < 4; mt++) {
#pragma unroll
        for (int nt = 0; nt < 2; nt++) {
            int gc = n0 + wn + nt * 16 + l16;
            float bias = bo[gc];
#pragma unroll
            for (int r = 0; r < 4; r++) {
                int gm = m0 + mt * 16 + quad * 4 + r;
                out[gm * DIM + gc] = acc[mt][nt][r] + bias;
            }
        }
    }
}

// ================= flash attention v4 (round-4 proven): 4 blocks/CU, chunk-fused =================
// grid 1024, 256 thr, 32 q-rows/wave. Each SIMD hosts waves from different blocks -> cross-block
// MFMA/VALU overlap. Per 16-key chunk, softmax pack feeds its 2 PV MFMAs immediately.
// Staging: swizzled global source + linear LDS dest (involution p^=(r&7)); dbuf, counted vmcnt(4).
__global__ __launch_bounds__(256, 4) void k_flash(const unsigned short* __restrict__ qk,
                                                  const unsigned short* __restrict__ vt,
                                                  unsigned short* __restrict__ Op,
                                                  float* __restrict__ Ls) {
    __shared__ unsigned short Ks[2][64 * 64];
    __shared__ unsigned short Vs[2][64 * 64];
    int tid = threadIdx.x;
    int lane = tid & 63, w = tid >> 6;
    int q31 = lane & 31, hi = lane >> 5;
    int bid = blockIdx.x;
    int xcd = bid & 7, sl = bid >> 3;
    int bh = xcd * 4 + (sl & 3);
    int qt = (sl >> 2) & 15;
    int sp = sl >> 6;

    const unsigned short* Qg = qk + bh * (TT * HD);
    const unsigned short* Kg = qk + NTOK * DIM + bh * (TT * HD) + sp * 1024 * HD;
    const unsigned short* Vg = vt + bh * (HD * TT) + sp * 1024;

    // Q B-frag (k=dim): lane n=q31 holds Q[qrow][16*ks + 8*hi + j]
    int qrow = qt * 128 + w * 32 + q31;
    bf8v qf[4];
#pragma unroll
    for (int ks = 0; ks < 4; ks++)
        qf[ks] = ld8(Qg + qrow * HD + ks * 16 + hi * 8);

    // staging: 512 chunks of 16B per tile; thread stages chunks tid and 256+tid.
    // chunk idx -> row r=idx>>3, phys slot p=idx&7, logical chunk c=p^(r&7) (involution).
    int r0 = tid >> 3, sw = (tid & 7) ^ (r0 & 7);
    int offK0 = r0 * HD + sw * 8, offK1 = offK0 + 32 * HD;
    int offV0 = r0 * TT + sw * 8, offV1 = offV0 + 32 * TT;
    int dst0 = tid * 8, dst1 = dst0 + 2048;

#define STAGE(tile, bufsel) do {                                  \
        const unsigned short* kb_ = Kg + (tile) * 64 * HD;        \
        const unsigned short* vb_ = Vg + (tile) * 64;             \
        gl_lds(kb_ + offK0, &Ks[bufsel][dst0]);                   \
        gl_lds(kb_ + offK1, &Ks[bufsel][dst1]);                   \
        gl_lds(vb_ + offV0, &Vs[bufsel][dst0]);                   \
        gl_lds(vb_ + offV1, &Vs[bufsel][dst1]);                   \
    } while (0)

    STAGE(0, 0);
    STAGE(1, 1);

    f16v oacc[2] = {};               // [mtd] O^T dim tiles
    float lsg = 0.f;
    int xsw = q31 & 7;

    for (int it = 0; it < 16; it++) {
        int cur = it & 1;
        if (it == 15) { asm volatile("s_waitcnt vmcnt(0)" ::: "memory"); }
        else          { asm volatile("s_waitcnt vmcnt(4)" ::: "memory"); }
        __builtin_amdgcn_s_barrier();
        asm volatile("" ::: "memory");

        const unsigned short* Kb = Ks[cur];
        const unsigned short* Vb = Vs[cur];

        // K frags + QK^T: S^T[key][qrow], 2 key tiles x K=64 (4 steps)
        bf8v kf0[4], kf1[4];
#pragma unroll
        for (int ks = 0; ks < 4; ks++) {
            kf0[ks] = ld8(&Kb[(q31) * 64 + ((2 * ks + hi) ^ xsw) * 8]);
            kf1[ks] = ld8(&Kb[(32 + q31) * 64 + ((2 * ks + hi) ^ xsw) * 8]);
        }
        f16v s0 = {}, s1 = {};
#pragma unroll
        for (int ks = 0; ks < 4; ks++) {
            s0 = __builtin_amdgcn_mfma_f32_32x32x16_bf16(kf0[ks], qf[ks], s0, 0, 0, 0);
            s1 = __builtin_amdgcn_mfma_f32_32x32x16_bf16(kf1[ks], qf[ks], s1, 0, 0, 0);
        }

        // V^T A-frags (ds_read latency hides under softmax chunks)
        bf8v vf[2][4];
#pragma unroll
        for (int kk = 0; kk < 4; kk++) {
            vf[0][kk] = ld8(&Vb[(q31) * 64 + ((2 * kk + hi) ^ xsw) * 8]);
            vf[1][kk] = ld8(&Vb[(32 + q31) * 64 + ((2 * kk + hi) ^ xsw) * 8]);
        }

        // chunk-fused softmax -> PV. Per 16-key chunk kk = mt*2+sub:
        // reg r of s_mt holds S^T[key = 32mt + (r&3)+8(r>>2)+4hi][qrow]; p = 2^s (Q pre-scaled).
        // cvt_pk pairs -> e0..e3 (keys {0,1},{2,3},{8,9},{10,11}+4hi); swap(e0,e2)+swap(e1,e3)
        // -> P^T B-frag words (k=8hi+j). Then 2 PV MFMAs for this chunk overlap next chunk VALU.
#pragma unroll
        for (int mt = 0; mt < 2; mt++) {
#pragma unroll
            for (int sub = 0; sub < 2; sub++) {
                const f16v& s = mt ? s1 : s0;
                float pe[8];
#pragma unroll
                for (int j = 0; j < 8; j++)
                    pe[j] = __builtin_amdgcn_exp2f(s[sub * 8 + j]);
                float t01 = pe[0] + pe[1], t23 = pe[2] + pe[3];
                float t45 = pe[4] + pe[5], t67 = pe[6] + pe[7];
                lsg += (t01 + t23) + (t45 + t67);
                unsigned int e0, e1, e2, e3;
                asm("v_cvt_pk_bf16_f32 %0, %1, %2" : "=v"(e0) : "v"(pe[0]), "v"(pe[1]));
                asm("v_cvt_pk_bf16_f32 %0, %1, %2" : "=v"(e1) : "v"(pe[2]), "v"(pe[3]));
                asm("v_cvt_pk_bf16_f32 %0, %1, %2" : "=v"(e2) : "v"(pe[4]), "v"(pe[5]));
                asm("v_cvt_pk_bf16_f32 %0, %1, %2" : "=v"(e3) : "v"(pe[6]), "v"(pe[7]));
                asm("v_permlane32_swap_b32 %0, %1" : "+v"(e0), "+v"(e2));
                asm("v_permlane32_swap_b32 %0, %1" : "+v"(e1), "+v"(e3));
                u4v pv = {e0, e1, e2, e3};
                bf8v pb = __builtin_bit_cast(bf8v, pv);
                int kk = mt * 2 + sub;
                oacc[0] = __builtin_amdgcn_mfma_f32_32x32x16_bf16(vf[0][kk], pb, oacc[0], 0, 0, 0);
                oacc[1] = __builtin_amdgcn_mfma_f32_32x32x16_bf16(vf[1][kk], pb, oacc[1], 0, 0, 0);
            }
        }

        __builtin_amdgcn_s_barrier();
        asm volatile("" ::: "memory");
        if (it < 14) STAGE(it + 2, cur);
    }
#undef STAGE

    // epilogue: unnormalized bf16 O^T partial + fp32 lsum partial
    float lsum = lsg + __shfl_xor(lsg, 32, 64);
    int b = bh >> 4, h = bh & 15;
    unsigned short* dst = Op + sp * (NTOK * DIM) + ((b * TT) + qrow) * DIM + h * HD + hi * 4;
#pragma unroll
    for (int mtd = 0; mtd < 2; mtd++) {
#pragma unroll
        for (int g4 = 0; g4 < 4; g4++) {
            us4 ov;
#pragma unroll
            for (int r = 0; r < 4; r++)
                ov[r] = f2bf(oacc[mtd][g4 * 4 + r]);   // dim = 32*mtd + 8*g4 + 4*hi + r
            *(us4*)&dst[mtd * 32 + g4 * 8] = ov;
        }
    }
    if (hi == 0)
        Ls[sp * 65536 + bh * 2048 + qrow] = lsum;
}

extern "C" void kernel_launch(void* const* d_in, const int* in_sizes, int n_in,
                              void* d_out, int out_size, void* d_ws, size_t ws_size,
                              hipStream_t stream) {
    const float* x  = (const float*)d_in[0];
    const float* Wq = (const float*)d_in[1];
    const float* Wk = (const float*)d_in[2];
    const float* Wv = (const float*)d_in[3];
    const float* Wo = (const float*)d_in[4];
    const float* bo = (const float*)d_in[5];
    float* out = (float*)d_out;
    char* ws = (char*)d_ws;

    // Op (16MB) aliases Xb+Wqkvt: both are dead after k_gemm_qkv, flash writes Op after.
    unsigned short* Xb    = (unsigned short*)(ws);                 //  8 MB
    unsigned short* Wqkvt = (unsigned short*)(ws + 8388608);       //  6 MB
    unsigned short* Op    = (unsigned short*)(ws);                 // 16 MB (aliases Xb/Wqkvt)
    unsigned short* QK    = (unsigned short*)(ws + 16777216);      // 16 MB (Q then K)
    unsigned short* Vt    = (unsigned short*)(ws + 33554432);      //  8 MB (V transposed)
    unsigned short* Wo2t  = (unsigned short*)(ws + 50331648);      //  2 MB
    float*          rope  = (float*)(ws + 52428800);               // 512 KB
    float*          Rm    = (float*)(ws + 52953088);               // 16 KB
    float*          Ls    = (float*)(ws + 52969472);               // 512 KB

    hipLaunchKernelGGL(k_prep,     dim3(7696),   dim3(256), 0, stream, x, Xb, Wq, Wk, Wv, Wqkvt, rope, Rm);
    hipLaunchKernelGGL(k_R,        dim3(512),    dim3(256), 0, stream, rope, Rm);
    hipLaunchKernelGGL(k_wo2,      dim3(16, 16), dim3(256), 0, stream, Wo, Rm, Wo2t);
    hipLaunchKernelGGL(k_gemm_qkv, dim3(24, 32), dim3(256), 0, stream, Xb, Wqkvt, QK, Vt);
    hipLaunchKernelGGL(k_flash,    dim3(1024),   dim3(256), 0, stream, QK, Vt, Op, Ls);
    hipLaunchKernelGGL(k_gemm_out, dim3(512),    dim3(256), 0, stream, Op, Ls, Wo2t, bo, out);
}

// Round 10
// 190.206 us; speedup vs baseline: 1.2059x; 1.0662x over previous
//
#include <hip/hip_runtime.h>
#include <math.h>

#define DIM 1024
#define NH 16
#define HD 64
#define TT 2048
#define NTOK 4096   // B*T

typedef __bf16 bf8v __attribute__((ext_vector_type(8)));
typedef float f4v __attribute__((ext_vector_type(4)));
typedef float f16v __attribute__((ext_vector_type(16)));
typedef unsigned short us8 __attribute__((ext_vector_type(8)));
typedef unsigned short us4 __attribute__((ext_vector_type(4)));
typedef unsigned int u4v __attribute__((ext_vector_type(4)));

static __device__ __forceinline__ unsigned short f2bf(float f) {
    unsigned int u = __float_as_uint(f);
    u += 0x7FFFu + ((u >> 16) & 1u);   // RNE
    return (unsigned short)(u >> 16);
}
static __device__ __forceinline__ bf8v ld8(const unsigned short* p) {
    return __builtin_bit_cast(bf8v, *(const us8*)p);
}
// async global->LDS, 16B per lane; HW dest = wave-uniform base + lane*16
static __device__ __forceinline__ void gl_lds(const unsigned short* g, unsigned short* l) {
    __builtin_amdgcn_global_load_lds((const __attribute__((address_space(1))) unsigned int*)(g),
                                     (__attribute__((address_space(3))) unsigned int*)(l), 16, 0, 0);
}

// ---------- fused prep: x->bf16 | W transpose->bf16 | rope table | zero Rm ----------
__global__ void k_prep(const float* __restrict__ x, unsigned short* __restrict__ xb,
                       const float* __restrict__ Wq, const float* __restrict__ Wk,
                       const float* __restrict__ Wv, unsigned short* __restrict__ wt,
                       float* __restrict__ rope, float* __restrict__ Rm) {
    int tid = threadIdx.x;
    int bb = blockIdx.x;
    if (bb < 4096) {                       // cast x (4 floats/thread)
        int i = bb * 256 + tid;
        float4 v = ((const float4*)x)[i];
        us4 o;
        o[0] = f2bf(v.x); o[1] = f2bf(v.y); o[2] = f2bf(v.z); o[3] = f2bf(v.w);
        *(us4*)&xb[i * 4] = o;
    } else if (bb < 7168) {                // transpose Wq|Wk|Wv
        __shared__ float tile[32][33];
        bb -= 4096;
        int z = bb >> 10, rem = bb & 1023;
        int bx = rem & 31, by = rem >> 5;
        const float* W = (z == 0) ? Wq : ((z == 1) ? Wk : Wv);
        int tx = tid & 31, ty = tid >> 5;   // (32, 8)
        int c0 = bx * 32, k0 = by * 32;
#pragma unroll
        for (int j = 0; j < 4; j++)
            tile[ty + j * 8][tx] = W[(k0 + ty + j * 8) * DIM + c0 + tx];
        __syncthreads();
        unsigned short* out = wt + z * DIM * DIM;
#pragma unroll
        for (int j = 0; j < 4; j++)
            out[(c0 + ty + j * 8) * DIM + k0 + tx] = f2bf(tile[tx][ty + j * 8]);
    } else if (bb < 7680) {                // rope [TT][HD]
        int i = (bb - 7168) * 256 + tid;
        int s = i >> 6, d = i & 63;
        float inv = exp2f(-(float)(d & 31) * (13.287712379549449f / 32.0f));
        float a = (float)s * inv;
        rope[i] = (d < 32) ? cosf(a) : sinf(a);
    } else {                               // zero Rm (4096 floats) for k_R atomics
        Rm[(bb - 7680) * 256 + tid] = 0.f;
    }
}

// ---------------- R = rope^T rope (64x64), 8x s-parallel blocks, atomic partials ----------------
__global__ void k_R(const float* __restrict__ rope, float* __restrict__ R) {
    __shared__ float red[256];
    int d = blockIdx.x & 63, sg = blockIdx.x >> 6;    // 64 d x 8 s-groups
    int e = threadIdx.x & 63, sl = threadIdx.x >> 6;
    const float* rp = rope + (sg * 256 + sl * 64) * 64;
    float acc = 0.f;
    for (int s = 0; s < 64; s++)
        acc += rp[s * 64 + d] * rp[s * 64 + e];
    red[threadIdx.x] = acc;
    __syncthreads();
    if (sl == 0)
        atomicAdd(&R[d * 64 + e], (red[e] + red[e + 64]) + (red[e + 128] + red[e + 192]));
}

// ------------- Wo2t[j][r] = sum_e R[d][e] * Wo[h*64+e][j],  r = h*64+d -------------
__global__ void k_wo2(const float* __restrict__ Wo, const float* __restrict__ R,
                      unsigned short* __restrict__ wo2t) {
    __shared__ float Ws[64 * 65];   // Ws[e][j]
    __shared__ float Rt[64 * 65];   // Rt[e][d] = R[d*64+e]
    int tid = threadIdx.x;
    int h = blockIdx.y, j0 = blockIdx.x * 64;
    for (int idx = tid; idx < 4096; idx += 256) {
        int e = idx >> 6, j = idx & 63;
        Ws[e * 65 + j] = Wo[(h * 64 + e) * DIM + j0 + j];
        Rt[e * 65 + j] = R[j * 64 + e];
    }
    __syncthreads();
    int d = tid & 63, jb = (tid >> 6) * 16;
    float acc[16] = {};
    for (int e = 0; e < 64; e++) {
        float r = Rt[e * 65 + d];
#pragma unroll
        for (int jj = 0; jj < 16; jj++)
            acc[jj] += r * Ws[e * 65 + jb + jj];
    }
#pragma unroll
    for (int jj = 0; jj < 16; jj++)
        wo2t[(j0 + jb + jj) * DIM + h * 64 + d] = f2bf(acc[jj]);
}

// ================= GEMM core (m97-style): global_load_lds staging, XOR-swizzled LDS =================
// LDS layout: row-major [*][32] bf16, 16B chunk q of row r stored at phys slot q^(r&3).
// Frag read for logical quarter `quad` uses qx = quad^(l16&3) -> bank-uniform.

// QKV projection: N = 3072. Q (pre-scaled by c1), K scatter to [B][H][T][64];
// V TRANSPOSED to [B][H][64][T].
__global__ __launch_bounds__(256, 3) void k_gemm_qkv(const unsigned short* __restrict__ A,
                                                     const unsigned short* __restrict__ Bt,
                                                     unsigned short* __restrict__ qk,
                                                     unsigned short* __restrict__ vt) {
    __shared__ unsigned short As[128 * 32];
    __shared__ unsigned short Bs[128 * 32];
    const int K = 1024;
    int tid = threadIdx.x;
    int lane = tid & 63, w = tid >> 6;
    int quad = lane >> 4, l16 = lane & 15;
    int m0 = blockIdx.y * 128, n0 = blockIdx.x * 128;
    int wm = (w >> 1) * 64, wn = (w & 1) * 64;

    // two 16B staging chunks per thread, lane-contiguous per wave
    int s0 = tid, s1 = 256 + tid;
    int r0 = s0 >> 2, cc0 = ((s0 & 3) ^ (r0 & 3)) * 8;
    int r1 = s1 >> 2, cc1 = ((s1 & 3) ^ (r1 & 3)) * 8;
    const unsigned short* Ag0 = A + (m0 + r0) * K + cc0;
    const unsigned short* Ag1 = A + (m0 + r1) * K + cc1;
    const unsigned short* Bg0 = Bt + (n0 + r0) * K + cc0;
    const unsigned short* Bg1 = Bt + (n0 + r1) * K + cc1;
    int qx = quad ^ (l16 & 3);

    f4v acc[4][4] = {};
    for (int k0 = 0; k0 < K; k0 += 32) {
        __syncthreads();                       // prior iter frag reads done
        gl_lds(Ag0 + k0, &As[s0 * 8]);
        gl_lds(Ag1 + k0, &As[s1 * 8]);
        gl_lds(Bg0 + k0, &Bs[s0 * 8]);
        gl_lds(Bg1 + k0, &Bs[s1 * 8]);
        __syncthreads();                       // drains vmcnt -> tiles in LDS
        bf8v af[4], bf[4];
#pragma unroll
        for (int mt = 0; mt < 4; mt++)
            af[mt] = ld8(&As[(wm + mt * 16 + l16) * 32 + qx * 8]);
#pragma unroll
        for (int nt = 0; nt < 4; nt++)
            bf[nt] = ld8(&Bs[(wn + nt * 16 + l16) * 32 + qx * 8]);
#pragma unroll
        for (int mt = 0; mt < 4; mt++)
#pragma unroll
            for (int nt = 0; nt < 4; nt++)
                acc[mt][nt] = __builtin_amdgcn_mfma_f32_16x16x32_bf16(af[mt], bf[nt], acc[mt][nt], 0, 0, 0);
    }
#pragma unroll
    for (int mt = 0; mt < 4; mt++) {
#pragma unroll
        for (int nt = 0; nt < 4; nt++) {
            int gc = n0 + wn + nt * 16 + l16;
            int h = (gc >> 6) & 15;
            int d = gc & 63;
            if (gc < 2048) {             // Q or K: [mtx][B][H][T][64]; Q pre-scaled by c1
                float qs = (gc < 1024) ? 0.18033688011111793f : 1.0f;
                int mtx = gc >> 10;
                unsigned short* base = qk + mtx * (NTOK * DIM);
#pragma unroll
                for (int r = 0; r < 4; r++) {
                    int gm = m0 + wm + mt * 16 + quad * 4 + r;
                    int b = gm >> 11, t = gm & 2047;
                    base[((b * NH + h) * TT + t) * HD + d] = f2bf(acc[mt][nt][r] * qs);
                }
            } else {                     // V: transposed [B][H][64][T]
                int gm0 = m0 + wm + mt * 16 + quad * 4;
                int b = gm0 >> 11, t = gm0 & 2047;
                us4 ov;
#pragma unroll
                for (int r = 0; r < 4; r++)
                    ov[r] = f2bf(acc[mt][nt][r]);
                *(us4*)&vt[(((b * NH + h) * HD) + d) * TT + t] = ov;
            }
        }
    }
}

// Output projection v4: plain GEMM (A = final attn bf16, staged via gl_lds like B).
// XCD-grouped BM=64 decode kept from round-9 (proven): y = xcd*8+(slot&7), x = slot>>3.
__global__ __launch_bounds__(256, 2) void k_gemm_out(const unsigned short* __restrict__ A,
                                                     const unsigned short* __restrict__ Bt,
                                                     const float* __restrict__ bo,
                                                     float* __restrict__ out) {
    __shared__ unsigned short As[64 * 32];
    __shared__ unsigned short Bs[128 * 32];
    const int K = 1024;
    int tid = threadIdx.x;
    int lane = tid & 63, w = tid >> 6;
    int quad = lane >> 4, l16 = lane & 15;
    int bid = blockIdx.x;
    int xcd = bid & 7, slot = bid >> 3;
    int y = xcd * 8 + (slot & 7);        // 0..63 m-panel
    int x = slot >> 3;                   // 0..7  n-panel
    int m0 = y * 64, n0 = x * 128;
    int wn = w * 32;                     // wave covers 64 rows x 32 cols

    int rr = tid >> 2, cc = ((tid & 3) ^ (rr & 3)) * 8;
    const unsigned short* Ag0 = A + (m0 + rr) * K + cc;
    const unsigned short* Bg0 = Bt + (n0 + rr) * K + cc;
    const unsigned short* Bg1 = Bt + (n0 + 64 + rr) * K + cc;
    int qx = quad ^ (l16 & 3);

    f4v acc[4][2] = {};
    for (int k0 = 0; k0 < K; k0 += 32) {
        __syncthreads();                       // prior iter frag reads done
        gl_lds(Ag0 + k0, &As[tid * 8]);
        gl_lds(Bg0 + k0, &Bs[tid * 8]);
        gl_lds(Bg1 + k0, &Bs[(256 + tid) * 8]);
        __syncthreads();                       // drains vmcnt -> tiles in LDS
        bf8v af[4], bf[2];
#pragma unroll
        for (int mt = 0; mt < 4; mt++)
            af[mt] = ld8(&As[(mt * 16 + l16) * 32 + qx * 8]);
#pragma unroll
        for (int nt = 0; nt < 2; nt++)
            bf[nt] = ld8(&Bs[(wn + nt * 16 + l16) * 32 + qx * 8]);
#pragma unroll
        for (int mt = 0; mt < 4; mt++)
#pragma unroll
            for (int nt = 0; nt < 2; nt++)
                acc[mt][nt] = __builtin_amdgcn_mfma_f32_16x16x32_bf16(af[mt], bf[nt], acc[mt][nt], 0, 0, 0);
    }
#pragma unroll
    for (int mt = 0; mt < 4; mt++) {
#pragma unroll
        for (int nt = 0; nt < 2; nt++) {
            int gc = n0 + wn + nt * 16 + l16;
            float bias = bo[gc];
#pragma unroll
            for (int r = 0; r < 4; r++) {
                int gm = m0 + mt * 16 + quad * 4 + r;
                out[gm * DIM + gc] = acc[mt][nt][r] + bias;
            }
        }
    }
}

// ================= flash attention v6: full-KV per block, direct normalized output =================
// vs round-4/9 v4: NO KV split — each block iterates all 2048 keys (32 iters), so softmax rows
// complete in-register -> normalize by rcp(lsum) and write FINAL bf16 attn (8 MB) directly.
// Eliminates Op partials (32 MB), Ls, and the combine. Grid 512 (2 blocks/CU).
// Inner loop byte-identical to proven v4; only trip count + epilogue changed.
__global__ __launch_bounds__(256, 2) void k_flash(const unsigned short* __restrict__ qk,
                                                  const unsigned short* __restrict__ vt,
                                                  unsigned short* __restrict__ attn) {
    __shared__ unsigned short Ks[2][64 * 64];
    __shared__ unsigned short Vs[2][64 * 64];
    int tid = threadIdx.x;
    int lane = tid & 63, w = tid >> 6;
    int q31 = lane & 31, hi = lane >> 5;
    int bid = blockIdx.x;
    int xcd = bid & 7, sl = bid >> 3;
    int bh = xcd * 4 + (sl & 3);
    int qt = sl >> 2;                    // 0..15

    const unsigned short* Qg = qk + bh * (TT * HD);
    const unsigned short* Kg = qk + NTOK * DIM + bh * (TT * HD);
    const unsigned short* Vg = vt + bh * (HD * TT);

    // Q B-frag (k=dim): lane n=q31 holds Q[qrow][16*ks + 8*hi + j]
    int qrow = qt * 128 + w * 32 + q31;
    bf8v qf[4];
#pragma unroll
    for (int ks = 0; ks < 4; ks++)
        qf[ks] = ld8(Qg + qrow * HD + ks * 16 + hi * 8);

    // staging: 512 chunks of 16B per tile; thread stages chunks tid and 256+tid.
    // chunk idx -> row r=idx>>3, phys slot p=idx&7, logical chunk c=p^(r&7) (involution).
    int r0 = tid >> 3, sw = (tid & 7) ^ (r0 & 7);
    int offK0 = r0 * HD + sw * 8, offK1 = offK0 + 32 * HD;
    int offV0 = r0 * TT + sw * 8, offV1 = offV0 + 32 * TT;
    int dst0 = tid * 8, dst1 = dst0 + 2048;

#define STAGE(tile, bufsel) do {                                  \
        const unsigned short* kb_ = Kg + (tile) * 64 * HD;        \
        const unsigned short* vb_ = Vg + (tile) * 64;             \
        gl_lds(kb_ + offK0, &Ks[bufsel][dst0]);                   \
        gl_lds(kb_ + offK1, &Ks[bufsel][dst1]);                   \
        gl_lds(vb_ + offV0, &Vs[bufsel][dst0]);                   \
        gl_lds(vb_ + offV1, &Vs[bufsel][dst1]);                   \
    } while (0)

    STAGE(0, 0);
    STAGE(1, 1);

    f16v oacc[2] = {};               // [mtd] O^T dim tiles
    float lsg = 0.f;
    int xsw = q31 & 7;

    for (int it = 0; it < 32; it++) {
        int cur = it & 1;
        if (it == 31) { asm volatile("s_waitcnt vmcnt(0)" ::: "memory"); }
        else          { asm volatile("s_waitcnt vmcnt(4)" ::: "memory"); }
        __builtin_amdgcn_s_barrier();
        asm volatile("" ::: "memory");

        const unsigned short* Kb = Ks[cur];
        const unsigned short* Vb = Vs[cur];

        // K frags + QK^T: S^T[key][qrow], 2 key tiles x K=64 (4 steps)
        bf8v kf0[4], kf1[4];
#pragma unroll
        for (int ks = 0; ks < 4; ks++) {
            kf0[ks] = ld8(&Kb[(q31) * 64 + ((2 * ks + hi) ^ xsw) * 8]);
            kf1[ks] = ld8(&Kb[(32 + q31) * 64 + ((2 * ks + hi) ^ xsw) * 8]);
        }
        f16v s0 = {}, s1 = {};
#pragma unroll
        for (int ks = 0; ks < 4; ks++) {
            s0 = __builtin_amdgcn_mfma_f32_32x32x16_bf16(kf0[ks], qf[ks], s0, 0, 0, 0);
            s1 = __builtin_amdgcn_mfma_f32_32x32x16_bf16(kf1[ks], qf[ks], s1, 0, 0, 0);
        }

        // V^T A-frags (ds_read latency hides under softmax chunks)
        bf8v vf[2][4];
#pragma unroll
        for (int kk = 0; kk < 4; kk++) {
            vf[0][kk] = ld8(&Vb[(q31) * 64 + ((2 * kk + hi) ^ xsw) * 8]);
            vf[1][kk] = ld8(&Vb[(32 + q31) * 64 + ((2 * kk + hi) ^ xsw) * 8]);
        }

        // chunk-fused softmax -> PV. Per 16-key chunk kk = mt*2+sub:
        // reg r of s_mt holds S^T[key = 32mt + (r&3)+8(r>>2)+4hi][qrow]; p = 2^s (Q pre-scaled).
        // cvt_pk pairs -> e0..e3 (keys {0,1},{2,3},{8,9},{10,11}+4hi); swap(e0,e2)+swap(e1,e3)
        // -> P^T B-frag words (k=8hi+j). Then 2 PV MFMAs for this chunk overlap next chunk VALU.
#pragma unroll
        for (int mt = 0; mt < 2; mt++) {
#pragma unroll
            for (int sub = 0; sub < 2; sub++) {
                const f16v& s = mt ? s1 : s0;
                float pe[8];
#pragma unroll
                for (int j = 0; j < 8; j++)
                    pe[j] = __builtin_amdgcn_exp2f(s[sub * 8 + j]);
                float t01 = pe[0] + pe[1], t23 = pe[2] + pe[3];
                float t45 = pe[4] + pe[5], t67 = pe[6] + pe[7];
                lsg += (t01 + t23) + (t45 + t67);
                unsigned int e0, e1, e2, e3;
                asm("v_cvt_pk_bf16_f32 %0, %1, %2" : "=v"(e0) : "v"(pe[0]), "v"(pe[1]));
                asm("v_cvt_pk_bf16_f32 %0, %1, %2" : "=v"(e1) : "v"(pe[2]), "v"(pe[3]));
                asm("v_cvt_pk_bf16_f32 %0, %1, %2" : "=v"(e2) : "v"(pe[4]), "v"(pe[5]));
                asm("v_cvt_pk_bf16_f32 %0, %1, %2" : "=v"(e3) : "v"(pe[6]), "v"(pe[7]));
                asm("v_permlane32_swap_b32 %0, %1" : "+v"(e0), "+v"(e2));
                asm("v_permlane32_swap_b32 %0, %1" : "+v"(e1), "+v"(e3));
                u4v pv = {e0, e1, e2, e3};
                bf8v pb = __builtin_bit_cast(bf8v, pv);
                int kk = mt * 2 + sub;
                oacc[0] = __builtin_amdgcn_mfma_f32_32x32x16_bf16(vf[0][kk], pb, oacc[0], 0, 0, 0);
                oacc[1] = __builtin_amdgcn_mfma_f32_32x32x16_bf16(vf[1][kk], pb, oacc[1], 0, 0, 0);
            }
        }

        __builtin_amdgcn_s_barrier();
        asm volatile("" ::: "memory");
        if (it < 30) STAGE(it + 2, cur);
    }
#undef STAGE

    // epilogue: complete row sums -> normalize in-register, write FINAL bf16 attn
    float lsum = lsg + __shfl_xor(lsg, 32, 64);
    float inv = __builtin_amdgcn_rcpf(lsum);
    int b = bh >> 4, h = bh & 15;
    unsigned short* dst = attn + ((b * TT) + qrow) * DIM + h * HD + hi * 4;
#pragma unroll
    for (int mtd = 0; mtd < 2; mtd++) {
#pragma unroll
        for (int g4 = 0; g4 < 4; g4++) {
            us4 ov;
#pragma unroll
            for (int r = 0; r < 4; r++)
                ov[r] = f2bf(oacc[mtd][g4 * 4 + r] * inv);   // dim = 32*mtd + 8*g4 + 4*hi + r
            *(us4*)&dst[mtd * 32 + g4 * 8] = ov;
        }
    }
}

extern "C" void kernel_launch(void* const* d_in, const int* in_sizes, int n_in,
                              void* d_out, int out_size, void* d_ws, size_t ws_size,
                              hipStream_t stream) {
    const float* x  = (const float*)d_in[0];
    const float* Wq = (const float*)d_in[1];
    const float* Wk = (const float*)d_in[2];
    const float* Wv = (const float*)d_in[3];
    const float* Wo = (const float*)d_in[4];
    const float* bo = (const float*)d_in[5];
    float* out = (float*)d_out;
    char* ws = (char*)d_ws;

    // attn (8MB) aliases Xb: Xb dead after k_gemm_qkv, flash writes attn after.
    unsigned short* Xb    = (unsigned short*)(ws);                 //  8 MB
    unsigned short* Wqkvt = (unsigned short*)(ws + 8388608);       //  6 MB
    unsigned short* attn  = (unsigned short*)(ws);                 //  8 MB (aliases Xb)
    unsigned short* QK    = (unsigned short*)(ws + 16777216);      // 16 MB (Q then K)
    unsigned short* Vt    = (unsigned short*)(ws + 33554432);      //  8 MB (V transposed)
    unsigned short* Wo2t  = (unsigned short*)(ws + 50331648);      //  2 MB
    float*          rope  = (float*)(ws + 52428800);               // 512 KB
    float*          Rm    = (float*)(ws + 52953088);               // 16 KB

    hipLaunchKernelGGL(k_prep,     dim3(7696),   dim3(256), 0, stream, x, Xb, Wq, Wk, Wv, Wqkvt, rope, Rm);
    hipLaunchKernelGGL(k_R,        dim3(512),    dim3(256), 0, stream, rope, Rm);
    hipLaunchKernelGGL(k_wo2,      dim3(16, 16), dim3(256), 0, stream, Wo, Rm, Wo2t);
    hipLaunchKernelGGL(k_gemm_qkv, dim3(24, 32), dim3(256), 0, stream, Xb, Wqkvt, QK, Vt);
    hipLaunchKernelGGL(k_flash,    dim3(512),    dim3(256), 0, stream, QK, Vt, attn);
    hipLaunchKernelGGL(k_gemm_out, dim3(512),    dim3(256), 0, stream, attn, Wo2t, bo, out);
}